// Round 4
// baseline (445.793 us; speedup 1.0000x reference)
//
#include <hip/hip_runtime.h>
#include <hip/hip_bf16.h>
#include <stdint.h>

// Shapes (hard-coded for this problem)
#define T_  4
#define B_  64
#define C_  384
#define N_  196        // H*W = 14*14
#define NH  8
#define DH  48
#define TB_ (T_*B_)          // 256
#define R_  (T_*B_*N_)       // 50176 pixels total
#define NW  12               // 384 bits -> 12 u32 words per pixel
#define P_  12544            // B_*N_ pixels per timestep
#define SBLK1 3136           // conv_statsO blocks: 16 pixels each
#define SA_  64              // statsA blocks: each sums SBLK1/SA_ = 49 rows

typedef float f32x2 __attribute__((ext_vector_type(2)));

// ---------------------------------------------------------------------------
// K0: transpose all 4 weights W[o][c] -> WT[m][c][o]
__global__ void transpose_w4(const float* __restrict__ s0, const float* __restrict__ s1,
                             const float* __restrict__ s2, const float* __restrict__ s3,
                             float* __restrict__ dst){
    int m = blockIdx.y;
    const float* src = (m==0)?s0:(m==1)?s1:(m==2)?s2:s3;
    int idx = blockIdx.x*256 + threadIdx.x;
    if (idx >= C_*C_) return;
    int o = idx % C_, c = idx / C_;
    dst[(size_t)m*C_*C_ + idx] = src[o*C_ + c];
}

// ---------------------------------------------------------------------------
// K1: pre-LIF on raw x -> spike bitmask [t][b][n][12 words]
__global__ __launch_bounds__(256) void pre_lif(const float* __restrict__ x,
                                               uint32_t* __restrict__ maskXS){
    int b = blockIdx.x / NW;
    int w = blockIdx.x % NW;
    int n = threadIdx.x;
    if (n >= N_) return;
    float v[32];
#pragma unroll
    for (int j=0;j<32;j++) v[j] = 0.f;
#pragma unroll
    for (int t=0;t<T_;t++){
        uint32_t word = 0;
#pragma unroll
        for (int j=0;j<32;j++){
            int c = w*32 + j;
            float xv = x[((size_t)(t*B_+b)*C_ + c)*N_ + n];
            v[j] = v[j] + (xv - v[j])*0.5f;
            if (v[j] >= 1.0f){ word |= (1u<<j); v[j] = 0.f; }
        }
        maskXS[((size_t)(t*B_+b)*N_ + n)*NW + w] = word;
    }
}

// ---------------------------------------------------------------------------
// K2a: sparse conv, BN partial stats ONLY (no Y write). 4 pixels per wave.
__global__ __launch_bounds__(256) void conv_statsO(const uint32_t* __restrict__ mask,
                                                   const float* __restrict__ WT,
                                                   float* __restrict__ p1,
                                                   float* __restrict__ p2){
    __shared__ float red1[4][C_];
    __shared__ float red2[4][C_];
    int tid = threadIdx.x, wave = tid>>6, lane = tid&63;
    int ob = 6*lane;
    f32x2 s10={0.f,0.f}, s11={0.f,0.f}, s12={0.f,0.f};
    f32x2 s20={0.f,0.f}, s21={0.f,0.f}, s22={0.f,0.f};
    for (int p=0;p<4;p++){
        int pix = (blockIdx.x*4 + wave)*4 + p;
        const uint4* m4 = (const uint4*)(mask + (size_t)pix*NW);
        uint4 ma = m4[0], mb = m4[1], mc = m4[2];
        uint32_t mwv[12] = {ma.x,ma.y,ma.z,ma.w, mb.x,mb.y,mb.z,mb.w, mc.x,mc.y,mc.z,mc.w};
        f32x2 y0={0.f,0.f}, y1={0.f,0.f}, y2={0.f,0.f};
        f32x2 z0={0.f,0.f}, z1={0.f,0.f}, z2={0.f,0.f};
#pragma unroll
        for (int w=0; w<NW; w++){
            uint32_t bits = mwv[w];
            while (bits){
                int c0 = (w<<5) + __builtin_ctz(bits); bits &= bits-1;
                const f32x2* col0 = (const f32x2*)(WT + (size_t)c0*C_ + ob);
                if (bits){
                    int c1 = (w<<5) + __builtin_ctz(bits); bits &= bits-1;
                    const f32x2* col1 = (const f32x2*)(WT + (size_t)c1*C_ + ob);
                    f32x2 a0=col0[0],a1=col0[1],a2=col0[2];
                    f32x2 b0=col1[0],b1=col1[1],b2=col1[2];
                    y0+=a0; y1+=a1; y2+=a2;
                    z0+=b0; z1+=b1; z2+=b2;
                } else {
                    y0+=col0[0]; y1+=col0[1]; y2+=col0[2];
                }
            }
        }
        y0+=z0; y1+=z1; y2+=z2;
        s10+=y0; s11+=y1; s12+=y2;
        s20+=y0*y0; s21+=y1*y1; s22+=y2*y2;
    }
    *(f32x2*)&red1[wave][ob  ] = s10;
    *(f32x2*)&red1[wave][ob+2] = s11;
    *(f32x2*)&red1[wave][ob+4] = s12;
    *(f32x2*)&red2[wave][ob  ] = s20;
    *(f32x2*)&red2[wave][ob+2] = s21;
    *(f32x2*)&red2[wave][ob+4] = s22;
    __syncthreads();
    for (int i=tid; i<C_; i+=256){
        p1[(size_t)blockIdx.x*C_ + i] = (red1[0][i]+red1[1][i])+(red1[2][i]+red1[3][i]);
        p2[(size_t)blockIdx.x*C_ + i] = (red2[0][i]+red2[1][i])+(red2[2][i]+red2[3][i]);
    }
}

// ---------------------------------------------------------------------------
// K3a: first-stage partial reduce (SBLK1 rows -> SA_ rows)
__global__ __launch_bounds__(384) void statsA(const float* __restrict__ p1,
                                              const float* __restrict__ p2,
                                              float* __restrict__ q1,
                                              float* __restrict__ q2){
    int o = threadIdx.x;
    int blk = blockIdx.x;
    const int ROWS = SBLK1 / SA_;   // 49
    size_t base = (size_t)blk*ROWS*C_ + o;
    float s1=0.f, s2=0.f;
#pragma unroll 4
    for (int r=0;r<ROWS;r++){
        s1 += p1[base + (size_t)r*C_];
        s2 += p2[base + (size_t)r*C_];
    }
    q1[blk*C_ + o] = s1;
    q2[blk*C_ + o] = s2;
}

// K3b: finalize BN -> fused scale/shift
__global__ __launch_bounds__(384) void statsB(const float* __restrict__ q1,
                                              const float* __restrict__ q2,
                                              const float* __restrict__ g,
                                              const float* __restrict__ bta,
                                              float* __restrict__ scale,
                                              float* __restrict__ shift){
    int o = threadIdx.x;
    float s1=0.f, s2=0.f;
#pragma unroll
    for (int b=0;b<SA_;b++){ s1 += q1[b*C_+o]; s2 += q2[b*C_+o]; }
    float m   = s1 / (float)R_;
    float var = s2 / (float)R_ - m*m;
    float sc  = g[o] / sqrtf(var + 1e-5f);
    scale[o] = sc;
    shift[o] = bta[o] - m*sc;
}

// ---------------------------------------------------------------------------
// K2b: sparse conv + fused BN scale/shift + LIF + spike pack.
// Wave = one (b,n) pixel, loops t. Lane owns o = 64*i + lane (i<6) for ballot.
__global__ __launch_bounds__(256) void conv_lif(const uint32_t* __restrict__ mask,
                                                const float* __restrict__ WT,
                                                const float* __restrict__ scale,
                                                const float* __restrict__ shift,
                                                uint32_t* __restrict__ mo){
    int tid = threadIdx.x, wave = tid>>6, lane = tid&63;
    int pix0 = blockIdx.x*4 + wave;         // b*N + n
    float sc[6], sh[6], v[6];
#pragma unroll
    for (int i=0;i<6;i++){
        sc[i] = scale[(i<<6)+lane];
        sh[i] = shift[(i<<6)+lane];
        v[i]  = 0.f;
    }
    for (int t=0;t<T_;t++){
        size_t pix = (size_t)t*P_ + pix0;
        const uint4* m4 = (const uint4*)(mask + pix*NW);
        uint4 ma = m4[0], mb = m4[1], mc = m4[2];
        uint32_t mwv[12] = {ma.x,ma.y,ma.z,ma.w, mb.x,mb.y,mb.z,mb.w, mc.x,mc.y,mc.z,mc.w};
        float y[6] = {0.f,0.f,0.f,0.f,0.f,0.f};
        float z[6] = {0.f,0.f,0.f,0.f,0.f,0.f};
#pragma unroll
        for (int w=0; w<NW; w++){
            uint32_t bits = mwv[w];
            while (bits){
                int c0 = (w<<5) + __builtin_ctz(bits); bits &= bits-1;
                const float* col0 = WT + (size_t)c0*C_ + lane;
                if (bits){
                    int c1 = (w<<5) + __builtin_ctz(bits); bits &= bits-1;
                    const float* col1 = WT + (size_t)c1*C_ + lane;
#pragma unroll
                    for (int i=0;i<6;i++){ y[i]+=col0[i<<6]; z[i]+=col1[i<<6]; }
                } else {
#pragma unroll
                    for (int i=0;i<6;i++) y[i]+=col0[i<<6];
                }
            }
        }
        uint32_t words[12];
#pragma unroll
        for (int i=0;i<6;i++){
            float val = (y[i]+z[i])*sc[i] + sh[i];
            v[i] = v[i] + (val - v[i])*0.5f;
            int s = (v[i] >= 1.0f);
            unsigned long long bal = __ballot(s);
            if (s) v[i] = 0.f;
            words[2*i]   = (uint32_t)bal;
            words[2*i+1] = (uint32_t)(bal>>32);
        }
        if (lane == 0){
            uint4* o4 = (uint4*)(mo + pix*NW);
            o4[0] = make_uint4(words[0],words[1],words[2],words[3]);
            o4[1] = make_uint4(words[4],words[5],words[6],words[7]);
            o4[2] = make_uint4(words[8],words[9],words[10],words[11]);
        }
    }
}

// ---------------------------------------------------------------------------
// K5: spiking attention + attn_lif via C = K^T V (exact integers).
__global__ __launch_bounds__(256) void attention_lif(const uint32_t* __restrict__ mq,
                                                     const uint32_t* __restrict__ mk,
                                                     const uint32_t* __restrict__ mv,
                                                     uint16_t* __restrict__ mo){
    __shared__ unsigned long long kT[DH][4];
    __shared__ unsigned long long vT[DH][4];
    __shared__ uint32_t Cp[DH*25];           // u16-pair packed C, row stride 25

    int h = blockIdx.x & 7;
    int b = blockIdx.x >> 3;
    int tid = threadIdx.x, wv = tid>>6, lane = tid&63;
    int sw  = (h*DH) >> 5;
    int shf = (h*DH) & 31;                   // 0 or 16

    float vm[DH];
#pragma unroll
    for (int d=0;d<DH;d++) vm[d] = 0.f;

    for (int t=0;t<T_;t++){
        int tb = t*B_ + b;
        unsigned long long q = 0, kk = 0, vvv = 0;
        if (tid < N_){
            const uint32_t* pq = mq + ((size_t)tb*N_ + tid)*NW + sw;
            const uint32_t* pk = mk + ((size_t)tb*N_ + tid)*NW + sw;
            const uint32_t* pv = mv + ((size_t)tb*N_ + tid)*NW + sw;
            unsigned long long lo, hi;
            lo = pq[0]; hi = pq[1];
            q   = (shf ? ((lo>>16) | (hi<<16)) : (lo | (hi<<32))) & 0xFFFFFFFFFFFFULL;
            lo = pk[0]; hi = pk[1];
            kk  = (shf ? ((lo>>16) | (hi<<16)) : (lo | (hi<<32))) & 0xFFFFFFFFFFFFULL;
            lo = pv[0]; hi = pv[1];
            vvv = (shf ? ((lo>>16) | (hi<<16)) : (lo | (hi<<32))) & 0xFFFFFFFFFFFFULL;
        }
#pragma unroll 1
        for (int d=0; d<DH; d++){
            unsigned long long bk_ = __ballot((int)((kk >>d)&1ull));
            unsigned long long bv_ = __ballot((int)((vvv>>d)&1ull));
            if (lane == 0){ kT[d][wv] = bk_; vT[d][wv] = bv_; }
        }
        __syncthreads();

        if (tid < 240){
            int j  = tid / 5;
            int dg = tid % 5;
            int d0 = dg*10;
            int d1 = (dg==4) ? 48 : d0+10;
            unsigned long long ka=kT[j][0], kb=kT[j][1], kc=kT[j][2], kd=kT[j][3];
            for (int d=d0; d<d1; d+=2){
                uint32_t c0 = (uint32_t)(__popcll(ka&vT[d][0]) + __popcll(kb&vT[d][1])
                            + __popcll(kc&vT[d][2]) + __popcll(kd&vT[d][3]));
                uint32_t c1 = (uint32_t)(__popcll(ka&vT[d+1][0]) + __popcll(kb&vT[d+1][1])
                            + __popcll(kc&vT[d+1][2]) + __popcll(kd&vT[d+1][3]));
                Cp[j*25 + (d>>1)] = c0 | (c1<<16);
            }
        }
        __syncthreads();

        if (tid < N_){
            uint32_t acc[24];
#pragma unroll
            for (int p=0;p<24;p++) acc[p] = 0u;
            unsigned long long qb = q;
            while (qb){
                int j = __builtin_ctzll(qb); qb &= qb-1;
                const uint32_t* row = &Cp[j*25];
#pragma unroll
                for (int p=0;p<24;p++) acc[p] += row[p];
            }
            unsigned long long sp = 0;
#pragma unroll
            for (int d=0; d<DH; d++){
                uint32_t a = (d&1) ? (acc[d>>1]>>16) : (acc[d>>1]&0xFFFFu);
                float o = 0.125f*(float)a;
                vm[d] = vm[d] + (o - vm[d])*0.5f;
                if (vm[d] >= 0.5f){ sp |= (1ull<<d); vm[d] = 0.f; }
            }
            size_t rec = ((size_t)tb*N_ + tid)*24 + 3*h;   // u16 index
            mo[rec]   = (uint16_t)(sp);
            mo[rec+1] = (uint16_t)(sp >> 16);
            mo[rec+2] = (uint16_t)(sp >> 32);
        }
        __syncthreads();
    }
}

// ---------------------------------------------------------------------------
// K6: proj conv + BN normalize + transposed write via LDS tile.
// Block = (tb, n-half, c-half): conv 98 pixels x 192 channels -> out[tb][c][n].
__global__ __launch_bounds__(256) void proj_out(const uint32_t* __restrict__ mask,
                                                const float* __restrict__ WT,
                                                const float* __restrict__ scale,
                                                const float* __restrict__ shift,
                                                float* __restrict__ out){
    __shared__ float tile[192][98];
    int bid = blockIdx.x;
    int tb = bid>>2, nh = (bid>>1)&1, ch = bid&1;
    int n0 = nh*98, c0 = ch*192;
    int tid = threadIdx.x, wave = tid>>6, lane = tid&63;
    float sc[3], sh[3];
#pragma unroll
    for (int i=0;i<3;i++){
        sc[i] = scale[c0+(i<<6)+lane];
        sh[i] = shift[c0+(i<<6)+lane];
    }
    for (int p=wave; p<98; p+=4){
        size_t pix = (size_t)tb*N_ + n0 + p;
        const uint4* m4 = (const uint4*)(mask + pix*NW);
        uint4 ma = m4[0], mb = m4[1], mc = m4[2];
        uint32_t mwv[12] = {ma.x,ma.y,ma.z,ma.w, mb.x,mb.y,mb.z,mb.w, mc.x,mc.y,mc.z,mc.w};
        float y[3] = {0.f,0.f,0.f};
        float z[3] = {0.f,0.f,0.f};
#pragma unroll
        for (int w=0; w<NW; w++){
            uint32_t bits = mwv[w];
            while (bits){
                int cc0 = (w<<5) + __builtin_ctz(bits); bits &= bits-1;
                const float* col0 = WT + (size_t)cc0*C_ + c0 + lane;
                if (bits){
                    int cc1 = (w<<5) + __builtin_ctz(bits); bits &= bits-1;
                    const float* col1 = WT + (size_t)cc1*C_ + c0 + lane;
#pragma unroll
                    for (int i=0;i<3;i++){ y[i]+=col0[i<<6]; z[i]+=col1[i<<6]; }
                } else {
#pragma unroll
                    for (int i=0;i<3;i++) y[i]+=col0[i<<6];
                }
            }
        }
#pragma unroll
        for (int i=0;i<3;i++)
            tile[(i<<6)+lane][p] = (y[i]+z[i])*sc[i] + sh[i];
    }
    __syncthreads();
    for (int r=wave; r<192; r+=4){
        if (lane < 49){
            f32x2 tv = *(const f32x2*)&tile[r][2*lane];
            *(f32x2*)(out + ((size_t)tb*C_ + c0 + r)*N_ + n0 + 2*lane) = tv;
        }
    }
}

// ---------------------------------------------------------------------------
extern "C" void kernel_launch(void* const* d_in, const int* in_sizes, int n_in,
                              void* d_out, int out_size, void* d_ws, size_t ws_size,
                              hipStream_t stream) {
    const float* x  = (const float*)d_in[0];
    const float* Wq = (const float*)d_in[1];
    const float* Wk = (const float*)d_in[2];
    const float* Wv = (const float*)d_in[3];
    const float* Wp = (const float*)d_in[4];
    const float* gq = (const float*)d_in[5];
    const float* bq = (const float*)d_in[6];
    const float* gk = (const float*)d_in[7];
    const float* bk = (const float*)d_in[8];
    const float* gv = (const float*)d_in[9];
    const float* bv = (const float*)d_in[10];
    const float* gp = (const float*)d_in[11];
    const float* bp = (const float*)d_in[12];

    // workspace carve (~25 MB)
    char* w = (char*)d_ws;
    size_t off = 0;
    uint32_t* maskXS = (uint32_t*)(w + off); off += (size_t)R_*NW*4; // 2.4 MB each
    uint32_t* maskQ  = (uint32_t*)(w + off); off += (size_t)R_*NW*4;
    uint32_t* maskK  = (uint32_t*)(w + off); off += (size_t)R_*NW*4;
    uint32_t* maskV  = (uint32_t*)(w + off); off += (size_t)R_*NW*4;
    float* WTall = (float*)(w + off); off += (size_t)4*C_*C_*4;      // 2.36 MB
    float* p1 = (float*)(w + off); off += (size_t)SBLK1*C_*4;        // 4.8 MB
    float* p2 = (float*)(w + off); off += (size_t)SBLK1*C_*4;
    float* q1 = (float*)(w + off); off += (size_t)SA_*C_*4;
    float* q2 = (float*)(w + off); off += (size_t)SA_*C_*4;
    float* scaleB = (float*)(w + off); off += C_*4;
    float* shiftB = (float*)(w + off); off += C_*4;
    uint32_t* maskOL = maskXS;      // alias: XS dead after v-branch conv_lif

    transpose_w4<<<dim3((C_*C_+255)/256, 4),256,0,stream>>>(Wq, Wk, Wv, Wp, WTall);

    pre_lif<<<B_*NW,256,0,stream>>>(x, maskXS);

    const float* Gs[3] = {gq, gk, gv};
    const float* Bs[3] = {bq, bk, bv};
    uint32_t* Ms[3] = {maskQ, maskK, maskV};
    for (int i=0;i<3;i++){
        const float* WT = WTall + (size_t)i*C_*C_;
        conv_statsO<<<SBLK1,256,0,stream>>>(maskXS, WT, p1, p2);
        statsA<<<SA_,384,0,stream>>>(p1, p2, q1, q2);
        statsB<<<1,384,0,stream>>>(q1, q2, Gs[i], Bs[i], scaleB, shiftB);
        conv_lif<<<P_/4,256,0,stream>>>(maskXS, WT, scaleB, shiftB, Ms[i]);
    }

    attention_lif<<<B_*NH,256,0,stream>>>(maskQ, maskK, maskV, (uint16_t*)maskOL);

    const float* WTp = WTall + (size_t)3*C_*C_;
    conv_statsO<<<SBLK1,256,0,stream>>>(maskOL, WTp, p1, p2);
    statsA<<<SA_,384,0,stream>>>(p1, p2, q1, q2);
    statsB<<<1,384,0,stream>>>(q1, q2, gp, bp, scaleB, shiftB);

    proj_out<<<TB_*4,256,0,stream>>>(maskOL, WTp, scaleB, shiftB, (float*)d_out);
}

// Round 5
// 422.642 us; speedup vs baseline: 1.0548x; 1.0548x over previous
//
#include <hip/hip_runtime.h>
#include <hip/hip_bf16.h>
#include <stdint.h>

// Shapes (hard-coded for this problem)
#define T_  4
#define B_  64
#define C_  384
#define N_  196        // H*W = 14*14
#define NH  8
#define DH  48
#define TB_ (T_*B_)          // 256
#define R_  (T_*B_*N_)       // 50176 pixels total
#define NW  12               // 384 bits -> 12 u32 words per pixel
#define P_  12544            // B_*N_ pixels per timestep
#define NCH 66               // pixel chunks of 768 (12 u64); 66*768 >= 50176
#define KG_ 17               // gram k-groups (4 chunks each)

typedef float f32x2 __attribute__((ext_vector_type(2)));

// ---------------------------------------------------------------------------
// K0: transpose all 4 weights W[o][c] -> WT[m][c][o]
__global__ void transpose_w4(const float* __restrict__ s0, const float* __restrict__ s1,
                             const float* __restrict__ s2, const float* __restrict__ s3,
                             float* __restrict__ dst){
    int m = blockIdx.y;
    const float* src = (m==0)?s0:(m==1)?s1:(m==2)?s2:s3;
    int idx = blockIdx.x*256 + threadIdx.x;
    if (idx >= C_*C_) return;
    int o = idx % C_, c = idx / C_;
    dst[(size_t)m*C_*C_ + idx] = src[o*C_ + c];
}

// ---------------------------------------------------------------------------
// K1: pre-LIF on raw x -> spike bitmask [t][b][n][12 words]
__global__ __launch_bounds__(256) void pre_lif(const float* __restrict__ x,
                                               uint32_t* __restrict__ maskXS){
    int b = blockIdx.x / NW;
    int w = blockIdx.x % NW;
    int n = threadIdx.x;
    if (n >= N_) return;
    float v[32];
#pragma unroll
    for (int j=0;j<32;j++) v[j] = 0.f;
#pragma unroll
    for (int t=0;t<T_;t++){
        uint32_t word = 0;
#pragma unroll
        for (int j=0;j<32;j++){
            int c = w*32 + j;
            float xv = x[((size_t)(t*B_+b)*C_ + c)*N_ + n];
            v[j] = v[j] + (xv - v[j])*0.5f;
            if (v[j] >= 1.0f){ word |= (1u<<j); v[j] = 0.f; }
        }
        maskXS[((size_t)(t*B_+b)*N_ + n)*NW + w] = word;
    }
}

// ---------------------------------------------------------------------------
// K2: bit-transpose masks: [pixel][384 bits] -> maskT[chunk][c][12 u64]
// wave gw handles 64 pixels; chunk kc=gw/12, word kw=gw%12. gw>=784 pads zeros.
__global__ __launch_bounds__(256) void bit_transpose(const uint32_t* __restrict__ mask,
                                                     unsigned long long* __restrict__ maskT){
    int gw = blockIdx.x*4 + (threadIdx.x>>6);      // 0..791
    int lane = threadIdx.x & 63;
    int kc = gw/12, kw = gw%12;
    uint32_t mwv[12];
#pragma unroll
    for (int w=0;w<12;w++) mwv[w]=0u;
    if (gw < 784){
        int pix = gw*64 + lane;
        const uint4* m4 = (const uint4*)(mask + (size_t)pix*NW);
        uint4 a=m4[0], b=m4[1], c=m4[2];
        mwv[0]=a.x; mwv[1]=a.y; mwv[2]=a.z; mwv[3]=a.w;
        mwv[4]=b.x; mwv[5]=b.y; mwv[6]=b.z; mwv[7]=b.w;
        mwv[8]=c.x; mwv[9]=c.y; mwv[10]=c.z; mwv[11]=c.w;
    }
#pragma unroll
    for (int w=0; w<12; w++){
        uint32_t word = mwv[w];
#pragma unroll
        for (int j=0; j<32; j++){
            unsigned long long bal = __ballot((int)((word>>j)&1u));
            if (lane == 0)
                maskT[((size_t)kc*C_ + (w*32+j))*12 + kw] = bal;
        }
    }
}

// ---------------------------------------------------------------------------
// K3: Gram partials: G[c][c'] = popcount co-occurrence. grid (KG_, 6 rg, 8 cg).
// Wave handles chunk kc = kg*4+wave; lane owns row rg*64+lane; 48 cols per block.
__global__ __launch_bounds__(256) void gram(const unsigned long long* __restrict__ maskT,
                                            unsigned int* __restrict__ Gpart){
    __shared__ unsigned int tile[64][49];
    int tid = threadIdx.x, wave = tid>>6, lane = tid&63;
    int kg = blockIdx.x, rg = blockIdx.y, cg = blockIdx.z;
    for (int i=tid; i<64*49; i+=256) ((unsigned int*)tile)[i] = 0u;
    __syncthreads();
    int kc = kg*4 + wave;
    if (kc < NCH){
        const uint4* rp = (const uint4*)(maskT + ((size_t)kc*C_ + rg*64 + lane)*12);
        uint32_t row[24];
#pragma unroll
        for (int q=0;q<6;q++){
            uint4 a = rp[q];
            row[4*q]=a.x; row[4*q+1]=a.y; row[4*q+2]=a.z; row[4*q+3]=a.w;
        }
        for (int cc=0; cc<48; cc++){
            const uint4* cp = (const uint4*)(maskT + ((size_t)kc*C_ + cg*48 + cc)*12);
            uint32_t col[24];
#pragma unroll
            for (int q=0;q<6;q++){
                uint4 a = cp[q];
                col[4*q]=a.x; col[4*q+1]=a.y; col[4*q+2]=a.z; col[4*q+3]=a.w;
            }
            unsigned int s = 0;
#pragma unroll
            for (int q=0;q<24;q++) s += (unsigned int)__popc(row[q]&col[q]);
            atomicAdd(&tile[lane][cc], s);
        }
    }
    __syncthreads();
    unsigned int* out = Gpart + (size_t)kg*C_*C_;
    for (int i=tid; i<64*48; i+=256){
        int r = i/48, cc = i%48;
        out[(size_t)(rg*64+r)*C_ + cg*48 + cc] = tile[r][cc];
    }
}

// K3b: reduce partials -> Gf (float, exact ints)
__global__ __launch_bounds__(256) void gram_reduce(const unsigned int* __restrict__ Gpart,
                                                   float* __restrict__ Gf){
    int e = blockIdx.x*256 + threadIdx.x;           // < 147456
    unsigned int s = 0;
#pragma unroll
    for (int k=0;k<KG_;k++) s += Gpart[(size_t)k*C_*C_ + e];
    Gf[e] = (float)s;
}

// ---------------------------------------------------------------------------
// K4: BN scale/shift from Gram: sum[o]=sum_c cnt[c] w[c], sumsq[o]=w^T G w.
// block = 4 outputs o, 384 threads (t = row c). grid (96, nbranch).
__global__ __launch_bounds__(384) void bn_from_gram(const float* __restrict__ Gf,
        const float* __restrict__ WTall,
        const float* __restrict__ g0, const float* __restrict__ b0,
        const float* __restrict__ g1, const float* __restrict__ b1,
        const float* __restrict__ g2, const float* __restrict__ b2,
        float* __restrict__ scaleOut, float* __restrict__ shiftOut, int wtBase){
    __shared__ float w4[384][4];
    __shared__ float sred[8][6];
    int t = threadIdx.x, wave = t>>6, lane = t&63;
    int br = blockIdx.y;
    const float* WT = WTall + (size_t)(wtBase+br)*C_*C_;
    int o0 = blockIdx.x*4;
    float4 wv = *(const float4*)(WT + (size_t)t*C_ + o0);
    w4[t][0]=wv.x; w4[t][1]=wv.y; w4[t][2]=wv.z; w4[t][3]=wv.w;
    __syncthreads();
    float h0=0.f,h1=0.f,h2=0.f,h3=0.f;
#pragma unroll 4
    for (int c=0;c<C_;c++){
        float gv = Gf[(size_t)c*C_ + t];
        float4 wc = *(const float4*)&w4[c][0];
        h0 += gv*wc.x; h1 += gv*wc.y; h2 += gv*wc.z; h3 += gv*wc.w;
    }
    float cnt = Gf[(size_t)t*C_ + t];
    float p0=wv.x*h0, p1=wv.y*h1, p2=wv.z*h2, p3=wv.w*h3;
    float q0=cnt*wv.x, q1=cnt*wv.y, q2=cnt*wv.z, q3=cnt*wv.w;
#pragma unroll
    for (int off=32; off>0; off>>=1){
        p0+=__shfl_down(p0,off); p1+=__shfl_down(p1,off);
        p2+=__shfl_down(p2,off); p3+=__shfl_down(p3,off);
        q0+=__shfl_down(q0,off); q1+=__shfl_down(q1,off);
        q2+=__shfl_down(q2,off); q3+=__shfl_down(q3,off);
    }
    if (lane == 0){
        sred[0][wave]=p0; sred[1][wave]=p1; sred[2][wave]=p2; sred[3][wave]=p3;
        sred[4][wave]=q0; sred[5][wave]=q1; sred[6][wave]=q2; sred[7][wave]=q3;
    }
    __syncthreads();
    if (t < 4){
        const float* g  = (br==0)?g0:(br==1)?g1:g2;
        const float* bb = (br==0)?b0:(br==1)?b1:b2;
        float ss = ((sred[t][0]+sred[t][1])+(sred[t][2]+sred[t][3]))+(sred[t][4]+sred[t][5]);
        float sm = ((sred[4+t][0]+sred[4+t][1])+(sred[4+t][2]+sred[4+t][3]))+(sred[4+t][4]+sred[4+t][5]);
        float m   = sm / (float)R_;
        float var = ss / (float)R_ - m*m;
        float sc  = g[o0+t] / sqrtf(var + 1e-5f);
        scaleOut[br*C_ + o0+t] = sc;
        shiftOut[br*C_ + o0+t] = bb[o0+t] - m*sc;
    }
}

// ---------------------------------------------------------------------------
// K5: sparse conv + fused BN + LIF + spike pack, all 3 branches (blockIdx.y).
// Wave = one (b,n) pixel, loops t. Lane owns o = 64*i + lane (i<6) for ballot.
// Active-channel list staged in LDS; gather loop unrolled x4 (24 loads in flight).
__global__ __launch_bounds__(256) void conv_lif(const uint32_t* __restrict__ mask,
                                                const float* __restrict__ WTall,
                                                const float* __restrict__ scaleAll,
                                                const float* __restrict__ shiftAll,
                                                uint32_t* __restrict__ moQ,
                                                uint32_t* __restrict__ moK,
                                                uint32_t* __restrict__ moV){
    __shared__ uint16_t lst[4][400];
    int br = blockIdx.y;
    const float* WT = WTall + (size_t)br*C_*C_;
    uint32_t* mo = (br==0)?moQ:(br==1)?moK:moV;
    int tid = threadIdx.x, wave = tid>>6, lane = tid&63;
    int pix0 = blockIdx.x*4 + wave;
    float sc[6], sh[6], v[6];
#pragma unroll
    for (int i=0;i<6;i++){
        sc[i] = scaleAll[br*C_ + (i<<6) + lane];
        sh[i] = shiftAll[br*C_ + (i<<6) + lane];
        v[i]  = 0.f;
    }
    for (int t=0;t<T_;t++){
        size_t pix = (size_t)t*P_ + pix0;
        const uint4* m4 = (const uint4*)(mask + pix*NW);
        uint4 ma = m4[0], mb = m4[1], mc = m4[2];
        uint32_t mwv[12] = {ma.x,ma.y,ma.z,ma.w, mb.x,mb.y,mb.z,mb.w, mc.x,mc.y,mc.z,mc.w};
        int cnt = 0;
#pragma unroll
        for (int w=0;w<12;w++) cnt += __popc(mwv[w]);
        if (lane == 0){
            int k = 0;
#pragma unroll
            for (int w=0;w<12;w++){
                uint32_t bits = mwv[w];
                while (bits){
                    lst[wave][k++] = (uint16_t)((w<<5) + __builtin_ctz(bits));
                    bits &= bits - 1;
                }
            }
        }
        float ya[6]={0,0,0,0,0,0}, yb[6]={0,0,0,0,0,0};
        float yc[6]={0,0,0,0,0,0}, yd[6]={0,0,0,0,0,0};
        int i = 0;
        for (; i+3 < cnt; i += 4){
            ushort4 cs = *(const ushort4*)&lst[wave][i];
            const float* q0 = WT + (size_t)cs.x*C_ + lane;
            const float* q1 = WT + (size_t)cs.y*C_ + lane;
            const float* q2 = WT + (size_t)cs.z*C_ + lane;
            const float* q3 = WT + (size_t)cs.w*C_ + lane;
#pragma unroll
            for (int j=0;j<6;j++){
                ya[j] += q0[j<<6]; yb[j] += q1[j<<6];
                yc[j] += q2[j<<6]; yd[j] += q3[j<<6];
            }
        }
        for (; i < cnt; ++i){
            int c = lst[wave][i];
            const float* q0 = WT + (size_t)c*C_ + lane;
#pragma unroll
            for (int j=0;j<6;j++) ya[j] += q0[j<<6];
        }
        uint32_t words[12];
#pragma unroll
        for (int j=0;j<6;j++){
            float val = ((ya[j]+yb[j]) + (yc[j]+yd[j]))*sc[j] + sh[j];
            v[j] = v[j] + (val - v[j])*0.5f;
            int s = (v[j] >= 1.0f);
            unsigned long long bal = __ballot(s);
            if (s) v[j] = 0.f;
            words[2*j]   = (uint32_t)bal;
            words[2*j+1] = (uint32_t)(bal>>32);
        }
        if (lane == 0){
            uint4* o4 = (uint4*)(mo + pix*NW);
            o4[0] = make_uint4(words[0],words[1],words[2],words[3]);
            o4[1] = make_uint4(words[4],words[5],words[6],words[7]);
            o4[2] = make_uint4(words[8],words[9],words[10],words[11]);
        }
    }
}

// ---------------------------------------------------------------------------
// K6: spiking attention + attn_lif via C = K^T V (exact integers).
__global__ __launch_bounds__(256) void attention_lif(const uint32_t* __restrict__ mq,
                                                     const uint32_t* __restrict__ mk,
                                                     const uint32_t* __restrict__ mv,
                                                     uint16_t* __restrict__ mo){
    __shared__ unsigned long long kT[DH][4];
    __shared__ unsigned long long vT[DH][4];
    __shared__ uint32_t Cp[DH*25];           // u16-pair packed C, row stride 25

    int h = blockIdx.x & 7;
    int b = blockIdx.x >> 3;
    int tid = threadIdx.x, wv = tid>>6, lane = tid&63;
    int sw  = (h*DH) >> 5;
    int shf = (h*DH) & 31;                   // 0 or 16

    float vm[DH];
#pragma unroll
    for (int d=0;d<DH;d++) vm[d] = 0.f;

    for (int t=0;t<T_;t++){
        int tb = t*B_ + b;
        unsigned long long q = 0, kk = 0, vvv = 0;
        if (tid < N_){
            const uint32_t* pq = mq + ((size_t)tb*N_ + tid)*NW + sw;
            const uint32_t* pk = mk + ((size_t)tb*N_ + tid)*NW + sw;
            const uint32_t* pv = mv + ((size_t)tb*N_ + tid)*NW + sw;
            unsigned long long lo, hi;
            lo = pq[0]; hi = pq[1];
            q   = (shf ? ((lo>>16) | (hi<<16)) : (lo | (hi<<32))) & 0xFFFFFFFFFFFFULL;
            lo = pk[0]; hi = pk[1];
            kk  = (shf ? ((lo>>16) | (hi<<16)) : (lo | (hi<<32))) & 0xFFFFFFFFFFFFULL;
            lo = pv[0]; hi = pv[1];
            vvv = (shf ? ((lo>>16) | (hi<<16)) : (lo | (hi<<32))) & 0xFFFFFFFFFFFFULL;
        }
#pragma unroll 1
        for (int d=0; d<DH; d++){
            unsigned long long bk_ = __ballot((int)((kk >>d)&1ull));
            unsigned long long bv_ = __ballot((int)((vvv>>d)&1ull));
            if (lane == 0){ kT[d][wv] = bk_; vT[d][wv] = bv_; }
        }
        __syncthreads();

        if (tid < 240){
            int j  = tid / 5;
            int dg = tid % 5;
            int d0 = dg*10;
            int d1 = (dg==4) ? 48 : d0+10;
            unsigned long long ka=kT[j][0], kb=kT[j][1], kc=kT[j][2], kd=kT[j][3];
            for (int d=d0; d<d1; d+=2){
                uint32_t c0 = (uint32_t)(__popcll(ka&vT[d][0]) + __popcll(kb&vT[d][1])
                            + __popcll(kc&vT[d][2]) + __popcll(kd&vT[d][3]));
                uint32_t c1 = (uint32_t)(__popcll(ka&vT[d+1][0]) + __popcll(kb&vT[d+1][1])
                            + __popcll(kc&vT[d+1][2]) + __popcll(kd&vT[d+1][3]));
                Cp[j*25 + (d>>1)] = c0 | (c1<<16);
            }
        }
        __syncthreads();

        if (tid < N_){
            uint32_t acc[24];
#pragma unroll
            for (int p=0;p<24;p++) acc[p] = 0u;
            unsigned long long qb = q;
            while (qb){
                int j = __builtin_ctzll(qb); qb &= qb-1;
                const uint32_t* row = &Cp[j*25];
#pragma unroll
                for (int p=0;p<24;p++) acc[p] += row[p];
            }
            unsigned long long sp = 0;
#pragma unroll
            for (int d=0; d<DH; d++){
                uint32_t a = (d&1) ? (acc[d>>1]>>16) : (acc[d>>1]&0xFFFFu);
                float o = 0.125f*(float)a;
                vm[d] = vm[d] + (o - vm[d])*0.5f;
                if (vm[d] >= 0.5f){ sp |= (1ull<<d); vm[d] = 0.f; }
            }
            size_t rec = ((size_t)tb*N_ + tid)*24 + 3*h;   // u16 index
            mo[rec]   = (uint16_t)(sp);
            mo[rec+1] = (uint16_t)(sp >> 16);
            mo[rec+2] = (uint16_t)(sp >> 32);
        }
        __syncthreads();
    }
}

// ---------------------------------------------------------------------------
// K7: proj conv + BN normalize + transposed write via LDS tile.
// Block = (tb, n-half, c-half): conv 98 pixels x 192 channels -> out[tb][c][n].
__global__ __launch_bounds__(256) void proj_out(const uint32_t* __restrict__ mask,
                                                const float* __restrict__ WT,
                                                const float* __restrict__ scale,
                                                const float* __restrict__ shift,
                                                float* __restrict__ out){
    __shared__ float tile[192][98];
    __shared__ uint16_t lst[4][400];
    int bid = blockIdx.x;
    int tb = bid>>2, nh = (bid>>1)&1, ch = bid&1;
    int n0 = nh*98, c0 = ch*192;
    int tid = threadIdx.x, wave = tid>>6, lane = tid&63;
    float sc[3], sh[3];
#pragma unroll
    for (int i=0;i<3;i++){
        sc[i] = scale[c0+(i<<6)+lane];
        sh[i] = shift[c0+(i<<6)+lane];
    }
    for (int p=wave; p<98; p+=4){
        size_t pix = (size_t)tb*N_ + n0 + p;
        const uint4* m4 = (const uint4*)(mask + pix*NW);
        uint4 ma = m4[0], mb = m4[1], mc = m4[2];
        uint32_t mwv[12] = {ma.x,ma.y,ma.z,ma.w, mb.x,mb.y,mb.z,mb.w, mc.x,mc.y,mc.z,mc.w};
        int cnt = 0;
#pragma unroll
        for (int w=0;w<12;w++) cnt += __popc(mwv[w]);
        if (lane == 0){
            int k = 0;
#pragma unroll
            for (int w=0;w<12;w++){
                uint32_t bits = mwv[w];
                while (bits){
                    lst[wave][k++] = (uint16_t)((w<<5) + __builtin_ctz(bits));
                    bits &= bits - 1;
                }
            }
        }
        float ya[3]={0,0,0}, yb[3]={0,0,0}, yc[3]={0,0,0}, yd[3]={0,0,0};
        int i = 0;
        for (; i+3 < cnt; i += 4){
            ushort4 cs = *(const ushort4*)&lst[wave][i];
            const float* q0 = WT + (size_t)cs.x*C_ + c0 + lane;
            const float* q1 = WT + (size_t)cs.y*C_ + c0 + lane;
            const float* q2 = WT + (size_t)cs.z*C_ + c0 + lane;
            const float* q3 = WT + (size_t)cs.w*C_ + c0 + lane;
#pragma unroll
            for (int j=0;j<3;j++){
                ya[j] += q0[j<<6]; yb[j] += q1[j<<6];
                yc[j] += q2[j<<6]; yd[j] += q3[j<<6];
            }
        }
        for (; i < cnt; ++i){
            int c = lst[wave][i];
            const float* q0 = WT + (size_t)c*C_ + c0 + lane;
#pragma unroll
            for (int j=0;j<3;j++) ya[j] += q0[j<<6];
        }
#pragma unroll
        for (int j=0;j<3;j++)
            tile[(j<<6)+lane][p] = ((ya[j]+yb[j])+(yc[j]+yd[j]))*sc[j] + sh[j];
    }
    __syncthreads();
    for (int r=wave; r<192; r+=4){
        if (lane < 49){
            f32x2 tv = *(const f32x2*)&tile[r][2*lane];
            *(f32x2*)(out + ((size_t)tb*C_ + c0 + r)*N_ + n0 + 2*lane) = tv;
        }
    }
}

// ---------------------------------------------------------------------------
extern "C" void kernel_launch(void* const* d_in, const int* in_sizes, int n_in,
                              void* d_out, int out_size, void* d_ws, size_t ws_size,
                              hipStream_t stream) {
    const float* x  = (const float*)d_in[0];
    const float* Wq = (const float*)d_in[1];
    const float* Wk = (const float*)d_in[2];
    const float* Wv = (const float*)d_in[3];
    const float* Wp = (const float*)d_in[4];
    const float* gq = (const float*)d_in[5];
    const float* bq = (const float*)d_in[6];
    const float* gk = (const float*)d_in[7];
    const float* bk = (const float*)d_in[8];
    const float* gv = (const float*)d_in[9];
    const float* bv = (const float*)d_in[10];
    const float* gp = (const float*)d_in[11];
    const float* bp = (const float*)d_in[12];

    // workspace carve (~25 MB)
    char* w = (char*)d_ws;
    size_t off = 0;
    uint32_t* maskXS = (uint32_t*)(w + off); off += (size_t)R_*NW*4;   // 2.41 MB each
    uint32_t* maskQ  = (uint32_t*)(w + off); off += (size_t)R_*NW*4;
    uint32_t* maskK  = (uint32_t*)(w + off); off += (size_t)R_*NW*4;
    uint32_t* maskV  = (uint32_t*)(w + off); off += (size_t)R_*NW*4;
    float* WTall = (float*)(w + off); off += (size_t)4*C_*C_*4;        // 2.36 MB
    unsigned long long* maskT = (unsigned long long*)(w + off); off += (size_t)NCH*C_*12*8; // 2.43 MB
    unsigned int* Gpart = (unsigned int*)(w + off); off += (size_t)KG_*C_*C_*4;             // 10.0 MB
    float* Gf = (float*)(w + off); off += (size_t)C_*C_*4;             // 0.59 MB
    float* scaleB = (float*)(w + off); off += (size_t)4*C_*4;
    float* shiftB = (float*)(w + off); off += (size_t)4*C_*4;
    uint32_t* maskOL = maskXS;      // alias: XS dead after conv_lif

    transpose_w4<<<dim3((C_*C_+255)/256, 4),256,0,stream>>>(Wq, Wk, Wv, Wp, WTall);

    pre_lif<<<B_*NW,256,0,stream>>>(x, maskXS);

    // stats for q,k,v branches via one shared Gram of maskXS
    bit_transpose<<<198,256,0,stream>>>(maskXS, maskT);
    gram<<<dim3(KG_,6,8),256,0,stream>>>(maskT, Gpart);
    gram_reduce<<<576,256,0,stream>>>(Gpart, Gf);
    bn_from_gram<<<dim3(96,3),384,0,stream>>>(Gf, WTall, gq,bq, gk,bk, gv,bv,
                                              scaleB, shiftB, 0);

    conv_lif<<<dim3(P_/4,3),256,0,stream>>>(maskXS, WTall, scaleB, shiftB,
                                            maskQ, maskK, maskV);

    attention_lif<<<B_*NH,256,0,stream>>>(maskQ, maskK, maskV, (uint16_t*)maskOL);

    // proj stats via Gram of maskOL
    bit_transpose<<<198,256,0,stream>>>(maskOL, maskT);
    gram<<<dim3(KG_,6,8),256,0,stream>>>(maskT, Gpart);
    gram_reduce<<<576,256,0,stream>>>(Gpart, Gf);
    bn_from_gram<<<dim3(96,1),384,0,stream>>>(Gf, WTall, gp,bp, gp,bp, gp,bp,
                                              scaleB + 3*C_, shiftB + 3*C_, 3);

    proj_out<<<TB_*4,256,0,stream>>>(maskOL, WTall + (size_t)3*C_*C_,
                                     scaleB + 3*C_, shiftB + 3*C_, (float*)d_out);
}